// Round 1
// baseline (371.780 us; speedup 1.0000x reference)
//
#include <hip/hip_runtime.h>
#include <math.h>

#define HID 64
#define HEADS 4
#define HDIM 16
#define N_MOL 2048
#define N_PROT 4096
#define E_MOL 32768
#define E_PROT 131072
#define BATCH 32
#define N_TOT (N_MOL + N_PROT)
#define E_TOT (E_MOL + E_PROT)

// attention tiling (r8-proven: 111us)
#define TQA 16         // queries per block
#define TKA 32         // keys per LDS tile
#define KSTA 68        // LDS row stride (words)
#define CH_MOL 4       // key chunks for mol queries (1024 keys each)
#define CH_PROT 2      // key chunks for prot queries (1024 keys each)
#define KCHUNK 1024
#define NGRP_MOL (N_MOL / TQA)          // 128

#define EPW 4          // edges per wave in k_msg

#define DOT4(a, b) ((a).x*(b).x + (a).y*(b).y + (a).z*(b).z + (a).w*(b).w)
#define EXP2(x) __builtin_amdgcn_exp2f(x)

// ---------------------------------------------------------------------------
// Node-linear only (bucketing removed — edge-parallel messages need no buckets).
__global__ void k_nl(const float* __restrict__ mol_x, const float* __restrict__ prot_x,
                     const float* __restrict__ Wm, const float* __restrict__ bm,
                     const float* __restrict__ Wp, const float* __restrict__ bp,
                     float* __restrict__ xm, float* __restrict__ xp) {
    int w = threadIdx.x >> 6, t = threadIdx.x & 63;
    int n = blockIdx.x * 4 + w;
    if (n < N_MOL) {
        const float* xr = mol_x + n * 11;
        float acc = bm[t];
#pragma unroll
        for (int i = 0; i < 11; ++i) acc += xr[i] * Wm[i * HID + t];
        xm[n * HID + t] = acc;
    } else {
        int p = n - N_MOL;
        const float* xr = prot_x + p * 15;
        float acc = bp[t];
#pragma unroll
        for (int i = 0; i < 15; ++i) acc += xr[i] * Wp[i * HID + t];
        xp[p * HID + t] = acc;
    }
}

// ---------------------------------------------------------------------------
// Edge-parallel GINE messages: msg = relu(x[src] + ea@We + be), atomic-scatter
// to agg[dst]. Edge id from blockIdx (no bucket indirection): dependent-load
// chain is 2 deep (src -> x gather), edges fully parallel across the grid.
__global__ __launch_bounds__(256) void k_msg(
    const float* __restrict__ xm, const float* __restrict__ xp,
    const float* __restrict__ mol_ea, const float* __restrict__ prot_ea,
    const int* __restrict__ mol_ei, const int* __restrict__ prot_ei,
    const float* __restrict__ Wem, const float* __restrict__ bem,
    const float* __restrict__ Wep, const float* __restrict__ bep,
    float* __restrict__ agg_m, float* __restrict__ agg_p) {
    int t = threadIdx.x & 63, w = threadIdx.x >> 6;
    int eb = blockIdx.x * (4 * EPW) + w * EPW;   // first edge of this wave
    const float* x; const float* ea; const int* ei;
    const float* We; const float* be; float* agg; int E;
    if (eb < E_MOL) {          // E_MOL % 16 == 0: block is type-uniform
        x = xm; ea = mol_ea; ei = mol_ei; We = Wem; be = bem; agg = agg_m; E = E_MOL;
    } else {
        eb -= E_MOL;
        x = xp; ea = prot_ea; ei = prot_ei; We = Wep; be = bep; agg = agg_p; E = E_PROT;
    }
    float bt = be[t];
    float wcol[10];
#pragma unroll
    for (int i = 0; i < 10; ++i) wcol[i] = We[i * HID + t];

    int s[EPW], d[EPW];
    float2 a[EPW][5];
#pragma unroll
    for (int i = 0; i < EPW; ++i) {
        int e = eb + i;
        s[i] = ei[e];
        d[i] = ei[E + e];
        const float2* p = (const float2*)(ea + (size_t)e * 10);
#pragma unroll
        for (int j = 0; j < 5; ++j) a[i][j] = p[j];
    }
#pragma unroll
    for (int i = 0; i < EPW; ++i) {
        float m = bt;
#pragma unroll
        for (int j = 0; j < 5; ++j) {
            m = fmaf(a[i][j].x, wcol[2 * j], m);
            m = fmaf(a[i][j].y, wcol[2 * j + 1], m);
        }
        float msg = fmaxf(m + x[(size_t)s[i] * HID + t], 0.f);
        unsafeAtomicAdd(&agg[(size_t)d[i] * HID + t], msg);
    }
}

// ---------------------------------------------------------------------------
// Node MLP: h = x + agg; relu(h@W1+b1)@W2+b2; relu. Re-zeroes agg for the
// next layer. doProj (layer 3): fused QKV projections (r5-verified map).
__global__ void k_node(const float* __restrict__ xin_m, const float* __restrict__ xin_p,
                       float* __restrict__ xout_m, float* __restrict__ xout_p,
                       float* __restrict__ agg_m, float* __restrict__ agg_p,
                       const float* __restrict__ W1m, const float* __restrict__ b1m,
                       const float* __restrict__ W2m, const float* __restrict__ b2m,
                       const float* __restrict__ W1p, const float* __restrict__ b1p,
                       const float* __restrict__ W2p, const float* __restrict__ b2p,
                       int doProj,
                       const float* __restrict__ mpW, const float* __restrict__ mpb,
                       const float* __restrict__ pmW, const float* __restrict__ pmb,
                       float* __restrict__ Qm, float* __restrict__ Kp, float* __restrict__ Vp,
                       float* __restrict__ Qp, float* __restrict__ Km, float* __restrict__ Vm) {
    __shared__ float h0[8][HID];
    __shared__ float h1[8][HID];
    int w = threadIdx.x >> 6, t = threadIdx.x & 63;
    int nb0 = blockIdx.x * 8 + w * 2;        // 2048 % 8 == 0: block is type-uniform
    bool isMol = nb0 < N_MOL;
    const float* x  = isMol ? xin_m : xin_p;
    float* xo       = isMol ? xout_m : xout_p;
    float* agg      = isMol ? agg_m : agg_p;
    int nbias = isMol ? 0 : N_MOL;
    int n0 = nb0 - nbias;

#pragma unroll
    for (int u = 0; u < 2; ++u) {
        size_t idx = (size_t)(n0 + u) * HID + t;
        h0[w * 2 + u][t] = x[idx] + agg[idx];
        agg[idx] = 0.f;                      // ready for next layer's k_msg
    }

    const float* W1 = isMol ? W1m : W1p;
    const float* W2 = isMol ? W2m : W2p;
    float b1v = isMol ? b1m[t] : b1p[t];
    float b2v = isMol ? b2m[t] : b2p[t];
    float acc0 = b1v, acc1 = b1v;
    const float4* hA = (const float4*)h0[w * 2];
    const float4* hB = (const float4*)h0[w * 2 + 1];
#pragma unroll
    for (int k = 0; k < 16; ++k) {
        float4 a = hA[k], b = hB[k];
        float w0 = W1[(4 * k + 0) * HID + t], w1 = W1[(4 * k + 1) * HID + t];
        float w2 = W1[(4 * k + 2) * HID + t], w3 = W1[(4 * k + 3) * HID + t];
        acc0 = fmaf(a.x, w0, acc0); acc1 = fmaf(b.x, w0, acc1);
        acc0 = fmaf(a.y, w1, acc0); acc1 = fmaf(b.y, w1, acc1);
        acc0 = fmaf(a.z, w2, acc0); acc1 = fmaf(b.z, w2, acc1);
        acc0 = fmaf(a.w, w3, acc0); acc1 = fmaf(b.w, w3, acc1);
    }
    h1[w * 2][t] = fmaxf(acc0, 0.f);
    h1[w * 2 + 1][t] = fmaxf(acc1, 0.f);
    float d0 = b2v, d1 = b2v;
    const float4* gA = (const float4*)h1[w * 2];
    const float4* gB = (const float4*)h1[w * 2 + 1];
#pragma unroll
    for (int k = 0; k < 16; ++k) {
        float4 a = gA[k], b = gB[k];
        float w0 = W2[(4 * k + 0) * HID + t], w1 = W2[(4 * k + 1) * HID + t];
        float w2 = W2[(4 * k + 2) * HID + t], w3 = W2[(4 * k + 3) * HID + t];
        d0 = fmaf(a.x, w0, d0); d1 = fmaf(b.x, w0, d1);
        d0 = fmaf(a.y, w1, d0); d1 = fmaf(b.y, w1, d1);
        d0 = fmaf(a.z, w2, d0); d1 = fmaf(b.z, w2, d1);
        d0 = fmaf(a.w, w3, d0); d1 = fmaf(b.w, w3, d1);
    }
    float xv0 = fmaxf(d0, 0.f), xv1 = fmaxf(d1, 0.f);
    xo[n0 * HID + t] = xv0;
    xo[(n0 + 1) * HID + t] = xv1;

    if (doProj) {
        // row-local QKV. mol rows feed Qm (mp.Q), Km (pm.K), Vm (pm.V);
        // prot rows feed Qp (pm.Q), Kp (mp.K), Vp (mp.V).  (r5-verified map)
        h0[w * 2][t] = xv0;                 // per-wave slice reuse, no barrier
        h0[w * 2 + 1][t] = xv1;
        const float *WQ, *bQ, *WK, *bK, *WV, *bV;
        float *dQ, *dK, *dV;
        if (isMol) { WQ = mpW;        bQ = mpb;       WK = pmW + 4096; bK = pmb + 64;
                     WV = pmW + 8192; bV = pmb + 128; dQ = Qm; dK = Km; dV = Vm; }
        else       { WQ = pmW;        bQ = pmb;       WK = mpW + 4096; bK = mpb + 64;
                     WV = mpW + 8192; bV = mpb + 128; dQ = Qp; dK = Kp; dV = Vp; }
        float aQ0 = bQ[t], aQ1 = aQ0;
        float aK0 = bK[t], aK1 = aK0;
        float aV0 = bV[t], aV1 = aV0;
        const float4* rA = (const float4*)h0[w * 2];
        const float4* rB = (const float4*)h0[w * 2 + 1];
#pragma unroll
        for (int k = 0; k < 16; ++k) {
            float4 a = rA[k], b = rB[k];
#pragma unroll
            for (int j = 0; j < 4; ++j) {
                float av = (j == 0) ? a.x : (j == 1) ? a.y : (j == 2) ? a.z : a.w;
                float bv = (j == 0) ? b.x : (j == 1) ? b.y : (j == 2) ? b.z : b.w;
                float wq = WQ[(4 * k + j) * HID + t];
                float wk = WK[(4 * k + j) * HID + t];
                float wv = WV[(4 * k + j) * HID + t];
                aQ0 = fmaf(av, wq, aQ0); aQ1 = fmaf(bv, wq, aQ1);
                aK0 = fmaf(av, wk, aK0); aK1 = fmaf(bv, wk, aK1);
                aV0 = fmaf(av, wv, aV0); aV1 = fmaf(bv, wv, aV1);
            }
        }
        dQ[n0 * HID + t] = aQ0; dQ[(n0 + 1) * HID + t] = aQ1;
        dK[n0 * HID + t] = aK0; dK[(n0 + 1) * HID + t] = aK1;
        dV[n0 * HID + t] = aV0; dV[(n0 + 1) * HID + t] = aV1;
    }
}

// ---------------------------------------------------------------------------
__device__ inline void upd4(float4& A, const float4 v0, const float4 v1,
                            float p0, float p1, float al) {
    A.x = fmaf(p1, v1.x, fmaf(p0, v0.x, A.x * al));
    A.y = fmaf(p1, v1.y, fmaf(p0, v0.y, A.y * al));
    A.z = fmaf(p1, v1.z, fmaf(p0, v0.z, A.z * al));
    A.w = fmaf(p1, v1.w, fmaf(p0, v0.w, A.w * al));
}
__device__ inline void merge4(float4& A, const float4 B, float c1, float c2) {
    A.x = A.x * c1 + B.x * c2;
    A.y = A.y * c1 + B.y * c2;
    A.z = A.z * c1 + B.z * c2;
    A.w = A.w * c1 + B.w * c2;
}
__device__ inline float4 shfl4(const float4 a, int off) {
    float4 r;
    r.x = __shfl_xor(a.x, off, 64); r.y = __shfl_xor(a.y, off, 64);
    r.z = __shfl_xor(a.z, off, 64); r.w = __shfl_xor(a.w, off, 64);
    return r;
}

// ---------------------------------------------------------------------------
// Tiled cross attention (r8-proven, unchanged): Q_LOCAL=4, double-buffered
// LDS, base-2 softmax via raw v_exp_f32, CH_MOL=4 / CH_PROT=2.
__global__ __launch_bounds__(256) void k_attn(
    const float* __restrict__ Qm, const float* __restrict__ Kp, const float* __restrict__ Vp,
    const float* __restrict__ Qp, const float* __restrict__ Km, const float* __restrict__ Vm,
    float* __restrict__ part_m, float* __restrict__ part_p) {
    __shared__ float Kl[2][TKA * KSTA];
    __shared__ float Vl[2][TKA * KSTA];

    int t = threadIdx.x;
    const float *Q, *K, *V;
    float* part;
    int q0, chunk, CH;
    {
        int b = blockIdx.x;
        const int MOLB = NGRP_MOL * CH_MOL;   // 512
        if (b < MOLB) {
            chunk = b & 3; q0 = (b >> 2) * TQA; CH = CH_MOL;
            Q = Qm; K = Kp; V = Vp; part = part_m;
        } else {
            b -= MOLB;
            chunk = b & 1; q0 = (b >> 1) * TQA; CH = CH_PROT;
            Q = Qp; K = Km; V = Vm; part = part_p;
        }
    }
    int kbeg = chunk * KCHUNK;

    int sub = t & 15, h = (t >> 4) & 3, qg = t >> 6;
    int r0 = t >> 4;                 // staging row 0..15 (and r0+16)
    int c0 = (t & 15) << 2;          // staging col (words)

    const float sc = 0.25f * 1.44269504088896f;   // 1/sqrt(16) * log2(e)
    float4 q4[4][4];
#pragma unroll
    for (int qq = 0; qq < 4; ++qq) {
        const float4* Qr = (const float4*)(Q + (q0 + qg * 4 + qq) * HID + h * HDIM);
#pragma unroll
        for (int j = 0; j < 4; ++j) {
            float4 v = Qr[j];
            v.x *= sc; v.y *= sc; v.z *= sc; v.w *= sc;
            q4[qq][j] = v;
        }
    }

    float mreg[4], lreg[4];
    float4 A[4][4];
#pragma unroll
    for (int qq = 0; qq < 4; ++qq) {
        mreg[qq] = -INFINITY; lreg[qq] = 0.f;
#pragma unroll
        for (int j = 0; j < 4; ++j) A[qq][j] = (float4){0.f, 0.f, 0.f, 0.f};
    }

    // prologue: stage tile 0 into buffer 0
    {
        const float4* Kg = (const float4*)(K + kbeg * HID);
        const float4* Vg = (const float4*)(V + kbeg * HID);
        float4 ka = Kg[t], kb = Kg[t + 256];
        float4 va = Vg[t], vb = Vg[t + 256];
        *(float4*)&Kl[0][r0 * KSTA + c0] = ka;
        *(float4*)&Kl[0][(r0 + 16) * KSTA + c0] = kb;
        *(float4*)&Vl[0][r0 * KSTA + c0] = va;
        *(float4*)&Vl[0][(r0 + 16) * KSTA + c0] = vb;
    }
    __syncthreads();

    const int NT = KCHUNK / TKA;     // 32 tiles
    for (int tile = 0; tile < NT; ++tile) {
        int cur = tile & 1;
        float4 ka, kb, va, vb;
        bool more = (tile + 1) < NT;
        if (more) {
            const float4* Kg = (const float4*)(K + (kbeg + (tile + 1) * TKA) * HID);
            const float4* Vg = (const float4*)(V + (kbeg + (tile + 1) * TKA) * HID);
            ka = Kg[t]; kb = Kg[t + 256];
            va = Vg[t]; vb = Vg[t + 256];
        }

        const float4* Kr0 = (const float4*)&Kl[cur][sub * KSTA + h * HDIM];
        const float4* Kr1 = (const float4*)&Kl[cur][(sub + 16) * KSTA + h * HDIM];
        float4 x0 = Kr0[0], x1 = Kr0[1], x2 = Kr0[2], x3 = Kr0[3];
        float4 y0 = Kr1[0], y1 = Kr1[1], y2 = Kr1[2], y3 = Kr1[3];

        float s0[4], s1[4];
#pragma unroll
        for (int qq = 0; qq < 4; ++qq) {
            s0[qq] = DOT4(x0, q4[qq][0]) + DOT4(x1, q4[qq][1]) + DOT4(x2, q4[qq][2]) + DOT4(x3, q4[qq][3]);
            s1[qq] = DOT4(y0, q4[qq][0]) + DOT4(y1, q4[qq][1]) + DOT4(y2, q4[qq][2]) + DOT4(y3, q4[qq][3]);
        }

        const float4* Vr0 = (const float4*)&Vl[cur][sub * KSTA + h * HDIM];
        const float4* Vr1 = (const float4*)&Vl[cur][(sub + 16) * KSTA + h * HDIM];
        float4 v00 = Vr0[0], v01 = Vr0[1], v02 = Vr0[2], v03 = Vr0[3];
        float4 v10 = Vr1[0], v11 = Vr1[1], v12 = Vr1[2], v13 = Vr1[3];

#pragma unroll
        for (int qq = 0; qq < 4; ++qq) {
            float mn = fmaxf(mreg[qq], fmaxf(s0[qq], s1[qq]));
            float al = EXP2(mreg[qq] - mn);
            float p0 = EXP2(s0[qq] - mn);
            float p1 = EXP2(s1[qq] - mn);
            lreg[qq] = lreg[qq] * al + p0 + p1;
            upd4(A[qq][0], v00, v10, p0, p1, al);
            upd4(A[qq][1], v01, v11, p0, p1, al);
            upd4(A[qq][2], v02, v12, p0, p1, al);
            upd4(A[qq][3], v03, v13, p0, p1, al);
            mreg[qq] = mn;
        }

        if (more) {
            int nxt = cur ^ 1;
            *(float4*)&Kl[nxt][r0 * KSTA + c0] = ka;
            *(float4*)&Kl[nxt][(r0 + 16) * KSTA + c0] = kb;
            *(float4*)&Vl[nxt][r0 * KSTA + c0] = va;
            *(float4*)&Vl[nxt][(r0 + 16) * KSTA + c0] = vb;
        }
        __syncthreads();
    }

    // merge 16 partial states across sub lanes (lane bits 0..3)
#pragma unroll
    for (int off = 1; off < 16; off <<= 1) {
#pragma unroll
        for (int qq = 0; qq < 4; ++qq) {
            float m2 = __shfl_xor(mreg[qq], off, 64);
            float l2 = __shfl_xor(lreg[qq], off, 64);
            float4 B0 = shfl4(A[qq][0], off), B1 = shfl4(A[qq][1], off);
            float4 B2 = shfl4(A[qq][2], off), B3 = shfl4(A[qq][3], off);
            float mn = fmaxf(mreg[qq], m2);
            float c1 = EXP2(mreg[qq] - mn), c2 = EXP2(m2 - mn);
            lreg[qq] = lreg[qq] * c1 + l2 * c2;
            merge4(A[qq][0], B0, c1, c2); merge4(A[qq][1], B1, c1, c2);
            merge4(A[qq][2], B2, c1, c2); merge4(A[qq][3], B3, c1, c2);
            mreg[qq] = mn;
        }
    }

    if (sub == 0) {
#pragma unroll
        for (int qq = 0; qq < 4; ++qq) {
            int qi = q0 + qg * 4 + qq;
            float* pp = part + (size_t)((qi * HEADS + h) * CH + chunk) * 20;
            pp[0] = mreg[qq]; pp[1] = lreg[qq];
            *(float4*)&pp[4] = A[qq][0]; *(float4*)&pp[8] = A[qq][1];
            *(float4*)&pp[12] = A[qq][2]; *(float4*)&pp[16] = A[qq][3];
        }
    }
}

// ---------------------------------------------------------------------------
// Parallel chunk-merge + residual + pool. Grid = BATCH*8: batch b=blk>>3,
// node-slice sl=blk&7. Partial sums -> LDS reduce -> 128 atomicAdds to pool.
// Slice 0 writes counts (single writer). All 256 CUs active.
__global__ void k_pool(const float* __restrict__ part_m, const float* __restrict__ part_p,
                       const float* __restrict__ xm, const float* __restrict__ xp,
                       const int* __restrict__ mb, const int* __restrict__ pb,
                       float* __restrict__ pool, float* __restrict__ cnt) {
    __shared__ float sm[64][65];
    int b = blockIdx.x >> 3, sl = blockIdx.x & 7;
    int t = threadIdx.x;
    int h = t & 3, s = t >> 2;
    int ms, me, ps, pe;
    {
        int lo = 0, hi = N_MOL;
        while (lo < hi) { int mid = (lo + hi) >> 1; if (mb[mid] < b) lo = mid + 1; else hi = mid; }
        ms = lo; lo = ms; hi = N_MOL;
        while (lo < hi) { int mid = (lo + hi) >> 1; if (mb[mid] < b + 1) lo = mid + 1; else hi = mid; }
        me = lo;
        lo = 0; hi = N_PROT;
        while (lo < hi) { int mid = (lo + hi) >> 1; if (pb[mid] < b) lo = mid + 1; else hi = mid; }
        ps = lo; lo = ps; hi = N_PROT;
        while (lo < hi) { int mid = (lo + hi) >> 1; if (pb[mid] < b + 1) lo = mid + 1; else hi = mid; }
        pe = lo;
    }
    if (sl == 0 && t == 0) { cnt[b * 2] = (float)(me - ms); cnt[b * 2 + 1] = (float)(pe - ps); }

    // ---- mol (CH_MOL chunks): nodes q with (q-ms) % 8 == sl, slot-strided
    {
        float acc[16];
#pragma unroll
        for (int d = 0; d < 16; ++d) acc[d] = 0.f;
        for (int q = ms + sl + 8 * s; q < me; q += 8 * 64) {
            const float* p0 = part_m + (size_t)(q * HEADS + h) * CH_MOL * 20;
            float mmax = -INFINITY;
#pragma unroll
            for (int c = 0; c < CH_MOL; ++c) mmax = fmaxf(mmax, p0[c * 20]);
            float lsum = 0.f, wgt[CH_MOL];
#pragma unroll
            for (int c = 0; c < CH_MOL; ++c) {
                wgt[c] = EXP2(p0[c * 20] - mmax);
                lsum += p0[c * 20 + 1] * wgt[c];
            }
            float inv = 1.f / lsum;
            const float* Xr = xm + q * HID + h * HDIM;
#pragma unroll
            for (int d = 0; d < 16; ++d) {
                float o = Xr[d];
#pragma unroll
                for (int c = 0; c < CH_MOL; ++c)
                    o = fmaf(p0[c * 20 + 4 + d], wgt[c] * inv, o);
                acc[d] += o;
            }
        }
#pragma unroll
        for (int d = 0; d < 16; ++d) sm[s][h * 16 + d] = acc[d];
    }
    __syncthreads();
    if (t < 64) {
        float sum = 0.f;
        for (int ss = 0; ss < 64; ++ss) sum += sm[ss][t];
        unsafeAtomicAdd(&pool[b * 128 + t], sum);
    }
    __syncthreads();

    // ---- prot (CH_PROT chunks)
    {
        float acc[16];
#pragma unroll
        for (int d = 0; d < 16; ++d) acc[d] = 0.f;
        for (int q = ps + sl + 8 * s; q < pe; q += 8 * 64) {
            const float* p0 = part_p + (size_t)(q * HEADS + h) * CH_PROT * 20;
            float m0 = p0[0], m1 = p0[20];
            float mmax = fmaxf(m0, m1);
            float w0 = EXP2(m0 - mmax), w1 = EXP2(m1 - mmax);
            float inv = 1.f / (p0[1] * w0 + p0[21] * w1);
            w0 *= inv; w1 *= inv;
            const float* Xr = xp + q * HID + h * HDIM;
#pragma unroll
            for (int d = 0; d < 16; ++d)
                acc[d] += Xr[d] + p0[4 + d] * w0 + p0[24 + d] * w1;
        }
#pragma unroll
        for (int d = 0; d < 16; ++d) sm[s][h * 16 + d] = acc[d];
    }
    __syncthreads();
    if (t < 64) {
        float sum = 0.f;
        for (int ss = 0; ss < 64; ++ss) sum += sm[ss][t];
        unsafeAtomicAdd(&pool[b * 128 + 64 + t], sum);
    }
}

// ---------------------------------------------------------------------------
// Head: z = pool/cnt; relu(z@fc1+b1)@fc2+b2 -> sigmoid. 32 blocks x 64.
__global__ void k_head(const float* __restrict__ pool, const float* __restrict__ cnt,
                       const float* __restrict__ fc1W, const float* __restrict__ fc1b,
                       const float* __restrict__ fc2W, const float* __restrict__ fc2b,
                       float* __restrict__ out) {
    __shared__ float z[128];
    int b = blockIdx.x, t = threadIdx.x;
    float cm = fmaxf(cnt[b * 2 + 0], 1.f), cp = fmaxf(cnt[b * 2 + 1], 1.f);
    z[t] = pool[b * 128 + t] / cm;
    z[64 + t] = pool[b * 128 + 64 + t] / cp;
    __syncthreads();
    float acc = fc1b[t];
    const float4* zv = (const float4*)z;
#pragma unroll
    for (int k = 0; k < 32; ++k) {
        float4 hv = zv[k];
        acc = fmaf(hv.x, fc1W[(4 * k + 0) * 64 + t], acc);
        acc = fmaf(hv.y, fc1W[(4 * k + 1) * 64 + t], acc);
        acc = fmaf(hv.z, fc1W[(4 * k + 2) * 64 + t], acc);
        acc = fmaf(hv.w, fc1W[(4 * k + 3) * 64 + t], acc);
    }
    float hv = fmaxf(acc, 0.f);
    float prod = hv * fc2W[t];
#pragma unroll
    for (int off = 32; off > 0; off >>= 1) prod += __shfl_xor(prod, off, 64);
    if (t == 0) out[b] = 1.f / (1.f + __expf(-(prod + fc2b[0])));
}

// ---------------------------------------------------------------------------
extern "C" void kernel_launch(void* const* d_in, const int* in_sizes, int n_in,
                              void* d_out, int out_size, void* d_ws, size_t ws_size,
                              hipStream_t stream) {
    const float* mol_x   = (const float*)d_in[0];
    const float* prot_x  = (const float*)d_in[1];
    const float* mol_ea  = (const float*)d_in[2];
    const float* prot_ea = (const float*)d_in[3];
    const int*   mol_ei  = (const int*)d_in[4];
    const int*   prot_ei = (const int*)d_in[5];
    const int*   mol_b   = (const int*)d_in[6];
    const int*   prot_b  = (const int*)d_in[7];
    const float* nlmW = (const float*)d_in[8];
    const float* nlmb = (const float*)d_in[9];
    const float* nlpW = (const float*)d_in[10];
    const float* nlpb = (const float*)d_in[11];
    const float* elmW = (const float*)d_in[12];
    const float* elmb = (const float*)d_in[13];
    const float* elpW = (const float*)d_in[14];
    const float* elpb = (const float*)d_in[15];
    const float* mcW1 = (const float*)d_in[16];
    const float* mcb1 = (const float*)d_in[17];
    const float* mcW2 = (const float*)d_in[18];
    const float* mcb2 = (const float*)d_in[19];
    const float* pcW1 = (const float*)d_in[20];
    const float* pcb1 = (const float*)d_in[21];
    const float* pcW2 = (const float*)d_in[22];
    const float* pcb2 = (const float*)d_in[23];
    const float* mpW  = (const float*)d_in[24];
    const float* mpb  = (const float*)d_in[25];
    const float* pmW  = (const float*)d_in[26];
    const float* pmb  = (const float*)d_in[27];
    const float* fc1W = (const float*)d_in[28];
    const float* fc1b = (const float*)d_in[29];
    const float* fc2W = (const float*)d_in[30];
    const float* fc2b = (const float*)d_in[31];

    float* ws    = (float*)d_ws;
    float* xa_m  = ws;                  // 131072
    float* xa_p  = xa_m + 131072;       // 262144
    float* xb_m  = xa_p + 262144;       // 131072
    float* xb_p  = xb_m + 131072;       // 262144
    float* Qm    = xb_p + 262144;       // 131072
    float* Kp    = Qm + 131072;         // 262144
    float* Vp    = Kp + 262144;         // 262144
    float* Qp    = Vp + 262144;         // 262144
    float* Km    = Qp + 262144;         // 131072
    float* Vm    = Km + 131072;         // 131072
    float* partm = Vm + 131072;         // 2048*4*4*20 = 655360
    float* partp = partm + 655360;      // 4096*4*2*20 = 655360
    float* pool  = partp + 655360;      // 4096 } contiguous memset
    float* cnt   = pool + 4096;         // 64   }
    // agg aliases partm: used only before k_attn (1.6 MB < 2.6 MB)
    float* agg_m = partm;               // 131072
    float* agg_p = partm + 131072;      // 262144

    hipMemsetAsync(pool, 0, (size_t)(4096 + 64) * 4, stream);
    hipMemsetAsync(agg_m, 0, (size_t)(131072 + 262144) * 4, stream);

    k_nl<<<N_TOT / 4, 256, 0, stream>>>(mol_x, prot_x, nlmW, nlmb, nlpW, nlpb, xa_m, xa_p);

    // layer 1: xa -> xb
    k_msg<<<E_TOT / (4 * EPW), 256, 0, stream>>>(xa_m, xa_p, mol_ea, prot_ea, mol_ei, prot_ei,
        elmW, elmb, elpW, elpb, agg_m, agg_p);
    k_node<<<N_TOT / 8, 256, 0, stream>>>(xa_m, xa_p, xb_m, xb_p, agg_m, agg_p,
        mcW1, mcb1, mcW2, mcb2, pcW1, pcb1, pcW2, pcb2,
        0, mpW, mpb, pmW, pmb, Qm, Kp, Vp, Qp, Km, Vm);
    // layer 2: xb -> xa
    k_msg<<<E_TOT / (4 * EPW), 256, 0, stream>>>(xb_m, xb_p, mol_ea, prot_ea, mol_ei, prot_ei,
        elmW, elmb, elpW, elpb, agg_m, agg_p);
    k_node<<<N_TOT / 8, 256, 0, stream>>>(xb_m, xb_p, xa_m, xa_p, agg_m, agg_p,
        mcW1 + 4096, mcb1 + 64, mcW2 + 4096, mcb2 + 64,
        pcW1 + 4096, pcb1 + 64, pcW2 + 4096, pcb2 + 64,
        0, mpW, mpb, pmW, pmb, Qm, Kp, Vp, Qp, Km, Vm);
    // layer 3: xa -> xb (+ fused QKV)
    k_msg<<<E_TOT / (4 * EPW), 256, 0, stream>>>(xa_m, xa_p, mol_ea, prot_ea, mol_ei, prot_ei,
        elmW, elmb, elpW, elpb, agg_m, agg_p);
    k_node<<<N_TOT / 8, 256, 0, stream>>>(xa_m, xa_p, xb_m, xb_p, agg_m, agg_p,
        mcW1 + 8192, mcb1 + 128, mcW2 + 8192, mcb2 + 128,
        pcW1 + 8192, pcb1 + 128, pcW2 + 8192, pcb2 + 128,
        1, mpW, mpb, pmW, pmb, Qm, Kp, Vp, Qp, Km, Vm);

    k_attn<<<NGRP_MOL * CH_MOL + (N_PROT / TQA) * CH_PROT, 256, 0, stream>>>(
        Qm, Kp, Vp, Qp, Km, Vm, partm, partp);

    k_pool<<<BATCH * 8, 256, 0, stream>>>(partm, partp, xb_m, xb_p, mol_b, prot_b, pool, cnt);
    k_head<<<BATCH, 64, 0, stream>>>(pool, cnt, fc1W, fc1b, fc2W, fc2b, (float*)d_out);
}